// Round 11
// baseline (27.601 us; speedup 1.0000x reference)
//
#include <hip/hip_runtime.h>

// DEQ fixed-point, per row (B=8.4M, LATENT=3):
//   c = W_in@d + b_in + b_fc;  u <- relu(W_fc@u + c);  out = W_out@u + b_out.
// R10: persistent generations + rotated unconditional prefetch.
// R9 showed T ~ 20.6us(mem floor) + mostly-unhidden ~7us VALU: one-shot
// blocks load->stall->compute->retire in lockstep, so HBM idles during each
// compute burst (eff 5.0 TB/s). Now: grid=2048 blocks (8/CU, stable
// residency), each thread runs GENS generations; the NEXT generation's three
// vf4 loads are issued UNCONDITIONALLY (clamped address, no branch, named
// registers) before computing the current one -> compiler emits vmcnt(3),
// loads land under a full generation of compute -> continuous HBM streaming.
// Numerics identical to R9 (K_ITERS=4, same op order) -> absmax 0.03125.

typedef float vf4 __attribute__((ext_vector_type(4)));

constexpr int RPT = 4;      // rows per thread per generation
constexpr int K_ITERS = 4;  // + init relu(c) = 5 applications total

__global__ __launch_bounds__(256, 8) void deq_fixed_point(
    const float* __restrict__ d,
    const float* __restrict__ W_fc,
    const float* __restrict__ b_fc,
    const float* __restrict__ W_in,
    const float* __restrict__ b_in,
    const float* __restrict__ W_out,
    const float* __restrict__ b_out,
    float* __restrict__ out,
    int nrows, int gens, long long rows_per_gen)
{
    const int t = blockIdx.x * blockDim.x + threadIdx.x;

    // ---- uniform weights: uniform addresses -> s_load -> SGPRs ----
    const float w00 = W_fc[0], w01 = W_fc[1], w02 = W_fc[2];
    const float w10 = W_fc[3], w11 = W_fc[4], w12 = W_fc[5];
    const float w20 = W_fc[6], w21 = W_fc[7], w22 = W_fc[8];
    const float i00 = W_in[0], i01 = W_in[1], i02 = W_in[2];
    const float i10 = W_in[3], i11 = W_in[4], i12 = W_in[5];
    const float i20 = W_in[6], i21 = W_in[7], i22 = W_in[8];
    const float cb0 = b_in[0] + b_fc[0];
    const float cb1 = b_in[1] + b_fc[1];
    const float cb2 = b_in[2] + b_fc[2];
    const float o0  = W_out[0], o1 = W_out[1], o2 = W_out[2];
    const float ob  = b_out[0];

    if (nrows < RPT) {  // degenerate tiny case (not hit at B=8.4M)
        if (t == 0) {
            for (int row = 0; row < nrows; ++row) {
                const float d0 = d[row * 3], d1 = d[row * 3 + 1], d2 = d[row * 3 + 2];
                const float c0 = fmaf(i00, d0, fmaf(i01, d1, fmaf(i02, d2, cb0)));
                const float c1 = fmaf(i10, d0, fmaf(i11, d1, fmaf(i12, d2, cb1)));
                const float c2 = fmaf(i20, d0, fmaf(i21, d1, fmaf(i22, d2, cb2)));
                float u0 = fmaxf(c0, 0.f), u1 = fmaxf(c1, 0.f), u2 = fmaxf(c2, 0.f);
                for (int it = 0; it < K_ITERS; ++it) {
                    const float a0 = fmaxf(fmaf(w00, u0, fmaf(w01, u1, fmaf(w02, u2, c0))), 0.f);
                    const float a1 = fmaxf(fmaf(w10, u0, fmaf(w11, u1, fmaf(w12, u2, c1))), 0.f);
                    const float a2 = fmaxf(fmaf(w20, u0, fmaf(w21, u1, fmaf(w22, u2, c2))), 0.f);
                    u0 = a0; u1 = a1; u2 = a2;
                }
                out[row] = fmaf(o0, u0, fmaf(o1, u1, fmaf(o2, u2, ob)));
            }
        }
        return;
    }

    // highest 16B-aligned in-bounds base for a full 4-row group
    const long long safe_last = ((long long)nrows - RPT) / RPT * RPT;

    long long gbase = (long long)t * RPT;

    // ---- prologue: load generation 0 (clamped) ----
    {
        const long long lb = gbase < safe_last ? gbase : safe_last;
        const vf4* dp = reinterpret_cast<const vf4*>(d + lb * 3);
        vf4 a0 = dp[0], a1 = dp[1], a2 = dp[2];

        for (int g = 0; g < gens; ++g) {
            // ---- unconditionally issue NEXT generation's loads (clamped) ----
            long long nb = gbase + rows_per_gen;
            nb = nb < safe_last ? nb : safe_last;
            const vf4* np = reinterpret_cast<const vf4*>(d + nb * 3);
            const vf4 n0 = np[0], n1 = np[1], n2 = np[2];

            // ---- compute current generation from a0..a2 ----
            if (gbase + RPT <= (long long)nrows) {
                float c[RPT][3];
                {
                    const float dr[RPT][3] = {
                        {a0.x, a0.y, a0.z}, {a0.w, a1.x, a1.y},
                        {a1.z, a1.w, a2.x}, {a2.y, a2.z, a2.w}};
                    #pragma unroll
                    for (int r = 0; r < RPT; ++r) {
                        c[r][0] = fmaf(i00, dr[r][0], fmaf(i01, dr[r][1], fmaf(i02, dr[r][2], cb0)));
                        c[r][1] = fmaf(i10, dr[r][0], fmaf(i11, dr[r][1], fmaf(i12, dr[r][2], cb1)));
                        c[r][2] = fmaf(i20, dr[r][0], fmaf(i21, dr[r][1], fmaf(i22, dr[r][2], cb2)));
                    }
                }
                float u[RPT][3];
                #pragma unroll
                for (int r = 0; r < RPT; ++r) {
                    u[r][0] = fmaxf(c[r][0], 0.f);
                    u[r][1] = fmaxf(c[r][1], 0.f);
                    u[r][2] = fmaxf(c[r][2], 0.f);
                }
                #pragma unroll
                for (int it = 0; it < K_ITERS; ++it) {
                    #pragma unroll
                    for (int r = 0; r < RPT; ++r) {
                        const float q0 = fmaxf(fmaf(w00, u[r][0], fmaf(w01, u[r][1], fmaf(w02, u[r][2], c[r][0]))), 0.f);
                        const float q1 = fmaxf(fmaf(w10, u[r][0], fmaf(w11, u[r][1], fmaf(w12, u[r][2], c[r][1]))), 0.f);
                        const float q2 = fmaxf(fmaf(w20, u[r][0], fmaf(w21, u[r][1], fmaf(w22, u[r][2], c[r][2]))), 0.f);
                        u[r][0] = q0; u[r][1] = q1; u[r][2] = q2;
                    }
                }
                vf4 o;
                o.x = fmaf(o0, u[0][0], fmaf(o1, u[0][1], fmaf(o2, u[0][2], ob)));
                o.y = fmaf(o0, u[1][0], fmaf(o1, u[1][1], fmaf(o2, u[1][2], ob)));
                o.z = fmaf(o0, u[2][0], fmaf(o1, u[2][1], fmaf(o2, u[2][2], ob)));
                o.w = fmaf(o0, u[3][0], fmaf(o1, u[3][1], fmaf(o2, u[3][2], ob)));
                *reinterpret_cast<vf4*>(out + gbase) = o;
            } else if (gbase < (long long)nrows) {
                // partial tail group (never hit when RPT*gens*threads == nrows)
                for (long long row = gbase; row < (long long)nrows; ++row) {
                    const float d0 = d[row * 3], d1 = d[row * 3 + 1], d2 = d[row * 3 + 2];
                    const float c0 = fmaf(i00, d0, fmaf(i01, d1, fmaf(i02, d2, cb0)));
                    const float c1 = fmaf(i10, d0, fmaf(i11, d1, fmaf(i12, d2, cb1)));
                    const float c2 = fmaf(i20, d0, fmaf(i21, d1, fmaf(i22, d2, cb2)));
                    float u0 = fmaxf(c0, 0.f), u1 = fmaxf(c1, 0.f), u2 = fmaxf(c2, 0.f);
                    for (int it = 0; it < K_ITERS; ++it) {
                        const float q0 = fmaxf(fmaf(w00, u0, fmaf(w01, u1, fmaf(w02, u2, c0))), 0.f);
                        const float q1 = fmaxf(fmaf(w10, u0, fmaf(w11, u1, fmaf(w12, u2, c1))), 0.f);
                        const float q2 = fmaxf(fmaf(w20, u0, fmaf(w21, u1, fmaf(w22, u2, c2))), 0.f);
                        u0 = q0; u1 = q1; u2 = q2;
                    }
                    out[row] = fmaf(o0, u0, fmaf(o1, u1, fmaf(o2, u2, ob)));
                }
            }

            // ---- rotate pipeline ----
            a0 = n0; a1 = n1; a2 = n2;
            gbase += rows_per_gen;
        }
    }
}

extern "C" void kernel_launch(void* const* d_in, const int* in_sizes, int n_in,
                              void* d_out, int out_size, void* d_ws, size_t ws_size,
                              hipStream_t stream) {
    const float* d     = (const float*)d_in[0];
    const float* W_fc  = (const float*)d_in[1];
    const float* b_fc  = (const float*)d_in[2];
    const float* W_in  = (const float*)d_in[3];
    const float* b_in  = (const float*)d_in[4];
    const float* W_out = (const float*)d_in[5];
    const float* b_out = (const float*)d_in[6];
    float* out = (float*)d_out;

    const int nrows = out_size;  // B (OUTPUT_DIM == 1)
    const int block = 256;
    const int grid  = 2048;      // 8 blocks/CU x 256 CUs: stable residency
    const long long threads_total = (long long)grid * block;
    const long long rows_per_gen = threads_total * RPT;
    int gens = (int)((nrows + rows_per_gen - 1) / rows_per_gen);
    if (gens < 1) gens = 1;

    deq_fixed_point<<<grid, block, 0, stream>>>(
        d, W_fc, b_fc, W_in, b_in, W_out, b_out, out, nrows, gens, rows_per_gen);
}

// Round 12
// 26.881 us; speedup vs baseline: 1.0268x; 1.0268x over previous
//
#include <hip/hip_runtime.h>

// DEQ fixed-point, per row (B=8.4M, LATENT=3):
//   c = W_in@d + b_in + b_fc;  u <- relu(W_fc@u + c);  out = W_out@u + b_out.
// R11: coalescing fix. R9 vs R10 proved overlap is NOT the limiter (full
// prefetch overlap = neutral), so the 5.0 TB/s (vs 6.29 copy ceiling) points
// at the strided read pattern: 16B loads at 48B lane-stride touch ~3x the
// cache lines per instruction. Fix: block stages 1024 rows (12KB) into LDS
// with 3 lane-contiguous vf4 loads per thread (1KB/instr, optimal), then
// reads rows from LDS at 48B stride (= 12-dword bank stride -> only 2-way
// conflict, free per m136). Compute identical to R9 (K=5 apps) -> absmax
// must be exactly 0.03125, which doubles as a shuffle-correctness check.

typedef float vf4 __attribute__((ext_vector_type(4)));

constexpr int RPT = 4;        // rows per thread
constexpr int K_ITERS = 4;    // + init relu(c) = 5 applications total
constexpr int BLOCK_ROWS = 1024;  // 256 threads * 4 rows

__global__ __launch_bounds__(256, 8) void deq_fixed_point(
    const float* __restrict__ d,
    const float* __restrict__ W_fc,
    const float* __restrict__ b_fc,
    const float* __restrict__ W_in,
    const float* __restrict__ b_in,
    const float* __restrict__ W_out,
    const float* __restrict__ b_out,
    float* __restrict__ out,
    int nrows)
{
    __shared__ float smem[BLOCK_ROWS * 3];  // 12 KB

    const int tid = threadIdx.x;
    const long long blockBase = (long long)blockIdx.x * BLOCK_ROWS;

    // ---- uniform weights: uniform addresses -> s_load -> SGPRs ----
    const float w00 = W_fc[0], w01 = W_fc[1], w02 = W_fc[2];
    const float w10 = W_fc[3], w11 = W_fc[4], w12 = W_fc[5];
    const float w20 = W_fc[6], w21 = W_fc[7], w22 = W_fc[8];
    const float i00 = W_in[0], i01 = W_in[1], i02 = W_in[2];
    const float i10 = W_in[3], i11 = W_in[4], i12 = W_in[5];
    const float i20 = W_in[6], i21 = W_in[7], i22 = W_in[8];
    const float cb0 = b_in[0] + b_fc[0];
    const float cb1 = b_in[1] + b_fc[1];
    const float cb2 = b_in[2] + b_fc[2];
    const float o0  = W_out[0], o1 = W_out[1], o2 = W_out[2];
    const float ob  = b_out[0];

    if (blockBase + BLOCK_ROWS <= (long long)nrows) {
        // ---- stage 12KB: 3 lane-contiguous vf4 loads -> LDS linear ----
        const vf4* gv = reinterpret_cast<const vf4*>(d + blockBase * 3);
        vf4* sv = reinterpret_cast<vf4*>(smem);
        const vf4 va = gv[tid], vb = gv[tid + 256], vc = gv[tid + 512];
        sv[tid]       = va;
        sv[tid + 256] = vb;
        sv[tid + 512] = vc;
        __syncthreads();

        // ---- read own 4 rows from LDS (48B stride = 2-way conflict, free) ----
        const float* rp = smem + tid * 12;
        const vf4 v0 = *reinterpret_cast<const vf4*>(rp);
        const vf4 v1 = *reinterpret_cast<const vf4*>(rp + 4);
        const vf4 v2 = *reinterpret_cast<const vf4*>(rp + 8);

        // ---- injection: c = W_in@d + (b_in+b_fc) ----
        float c[RPT][3];
        {
            const float dr[RPT][3] = {
                {v0.x, v0.y, v0.z}, {v0.w, v1.x, v1.y},
                {v1.z, v1.w, v2.x}, {v2.y, v2.z, v2.w}};
            #pragma unroll
            for (int r = 0; r < RPT; ++r) {
                c[r][0] = fmaf(i00, dr[r][0], fmaf(i01, dr[r][1], fmaf(i02, dr[r][2], cb0)));
                c[r][1] = fmaf(i10, dr[r][0], fmaf(i11, dr[r][1], fmaf(i12, dr[r][2], cb1)));
                c[r][2] = fmaf(i20, dr[r][0], fmaf(i21, dr[r][1], fmaf(i22, dr[r][2], cb2)));
            }
        }

        // ---- u = relu(c); then 4 iterations, 4 independent row chains ----
        float u[RPT][3];
        #pragma unroll
        for (int r = 0; r < RPT; ++r) {
            u[r][0] = fmaxf(c[r][0], 0.f);
            u[r][1] = fmaxf(c[r][1], 0.f);
            u[r][2] = fmaxf(c[r][2], 0.f);
        }
        #pragma unroll
        for (int it = 0; it < K_ITERS; ++it) {
            #pragma unroll
            for (int r = 0; r < RPT; ++r) {
                const float a0 = fmaxf(fmaf(w00, u[r][0], fmaf(w01, u[r][1], fmaf(w02, u[r][2], c[r][0]))), 0.f);
                const float a1 = fmaxf(fmaf(w10, u[r][0], fmaf(w11, u[r][1], fmaf(w12, u[r][2], c[r][1]))), 0.f);
                const float a2 = fmaxf(fmaf(w20, u[r][0], fmaf(w21, u[r][1], fmaf(w22, u[r][2], c[r][2]))), 0.f);
                u[r][0] = a0; u[r][1] = a1; u[r][2] = a2;
            }
        }

        // ---- head + float4 store (block writes 4KB contiguous) ----
        vf4 o;
        o.x = fmaf(o0, u[0][0], fmaf(o1, u[0][1], fmaf(o2, u[0][2], ob)));
        o.y = fmaf(o0, u[1][0], fmaf(o1, u[1][1], fmaf(o2, u[1][2], ob)));
        o.z = fmaf(o0, u[2][0], fmaf(o1, u[2][1], fmaf(o2, u[2][2], ob)));
        o.w = fmaf(o0, u[3][0], fmaf(o1, u[3][1], fmaf(o2, u[3][2], ob)));
        *reinterpret_cast<vf4*>(out + blockBase + tid * RPT) = o;
    } else {
        // ---- partial last block: per-thread scalar, no LDS/barrier ----
        const long long base = blockBase + (long long)tid * RPT;
        for (long long row = base; row < (long long)nrows && row < base + RPT; ++row) {
            const float d0 = d[row * 3], d1 = d[row * 3 + 1], d2 = d[row * 3 + 2];
            const float c0 = fmaf(i00, d0, fmaf(i01, d1, fmaf(i02, d2, cb0)));
            const float c1 = fmaf(i10, d0, fmaf(i11, d1, fmaf(i12, d2, cb1)));
            const float c2 = fmaf(i20, d0, fmaf(i21, d1, fmaf(i22, d2, cb2)));
            float u0 = fmaxf(c0, 0.f), u1 = fmaxf(c1, 0.f), u2 = fmaxf(c2, 0.f);
            for (int it = 0; it < K_ITERS; ++it) {
                const float a0 = fmaxf(fmaf(w00, u0, fmaf(w01, u1, fmaf(w02, u2, c0))), 0.f);
                const float a1 = fmaxf(fmaf(w10, u0, fmaf(w11, u1, fmaf(w12, u2, c1))), 0.f);
                const float a2 = fmaxf(fmaf(w20, u0, fmaf(w21, u1, fmaf(w22, u2, c2))), 0.f);
                u0 = a0; u1 = a1; u2 = a2;
            }
            out[row] = fmaf(o0, u0, fmaf(o1, u1, fmaf(o2, u2, ob)));
        }
    }
}

extern "C" void kernel_launch(void* const* d_in, const int* in_sizes, int n_in,
                              void* d_out, int out_size, void* d_ws, size_t ws_size,
                              hipStream_t stream) {
    const float* d     = (const float*)d_in[0];
    const float* W_fc  = (const float*)d_in[1];
    const float* b_fc  = (const float*)d_in[2];
    const float* W_in  = (const float*)d_in[3];
    const float* b_in  = (const float*)d_in[4];
    const float* W_out = (const float*)d_in[5];
    const float* b_out = (const float*)d_in[6];
    float* out = (float*)d_out;

    const int nrows = out_size;  // B (OUTPUT_DIM == 1)
    const int block = 256;
    const int grid = (int)(((long long)nrows + BLOCK_ROWS - 1) / BLOCK_ROWS);

    deq_fixed_point<<<grid, block, 0, stream>>>(
        d, W_fc, b_fc, W_in, b_in, W_out, b_out, out, nrows);
}